// Round 7
// baseline (127682.959 us; speedup 1.0000x reference)
//
#include <hip/hip_runtime.h>
#include <cstddef>

typedef float f32x4 __attribute__((ext_vector_type(4)));
typedef short bf16x8 __attribute__((ext_vector_type(8)));

namespace {
constexpr int D = 64;
constexpr int SB = 72;   // bf16 LDS row stride (shorts)
constexpr float JITTER = 1e-6f;
}

__device__ __forceinline__ unsigned fbits(float x){ union{float f;unsigned u;}v; v.f=x; return v.u; }
__device__ __forceinline__ float bitsf(unsigned u){ union{unsigned u;float f;}v; v.u=u; return v.f; }
__device__ __forceinline__ float bf2f(short h){ return bitsf(((unsigned)(unsigned short)h)<<16); }

__device__ __forceinline__ void split4(const f32x4 dv, uint2& hi, uint2& lo) {
  const unsigned b0 = fbits(dv[0]), b1 = fbits(dv[1]), b2 = fbits(dv[2]), b3 = fbits(dv[3]);
  hi.x = __builtin_amdgcn_perm(b1, b0, 0x07060302u);
  hi.y = __builtin_amdgcn_perm(b3, b2, 0x07060302u);
  const float r0 = dv[0] - bitsf(b0 & 0xFFFF0000u);
  const float r1 = dv[1] - bitsf(b1 & 0xFFFF0000u);
  const float r2 = dv[2] - bitsf(b2 & 0xFFFF0000u);
  const float r3 = dv[3] - bitsf(b3 & 0xFFFF0000u);
  lo.x = __builtin_amdgcn_perm(fbits(r1), fbits(r0), 0x07060302u);
  lo.y = __builtin_amdgcn_perm(fbits(r3), fbits(r2), 0x07060302u);
}

__device__ __forceinline__ void split8t(const float* src, bf16x8& hi, bf16x8& lo) {
  #pragma unroll
  for (int j = 0; j < 8; ++j) {
    const unsigned b = fbits(src[j]);
    hi[j] = (short)(b >> 16);
    const float r = src[j] - bitsf(b & 0xFFFF0000u);
    lo[j] = (short)(fbits(r) >> 16);
  }
}

// Barrier without the vmcnt(0) drain (LDS ordering only).
__device__ __forceinline__ void barrier_lds() {
  asm volatile("s_waitcnt lgkmcnt(0)\n\ts_barrier" ::: "memory");
}

// 8 waves: 0-3 MFMA (2x2 quadrants of 64x64), wave 4 = aux (mu/out/S-scalars),
// wave 5 = prefetch, waves 6-7 idle (barrier only). 2 barriers/step.
// seg1: MFMA: M1 = P@F^T; w-partials from acc; C0==32 pair: v = P_hi h (from A-frags) + S-reduce; M1T store
//       aux:  mu(t) = Fmu + kg_prev*w_prev; mu bf16-split store; hmu = h.mu reduce; y
//       pre:  load h(t+1)
// seg2: MFMA: acc2 = Q - w w^T/S + F@M1; C0==0 pair: +Fmu = F@mu column; P' store, Fmu store
//       aux:  S,kg; out = mu + kg v
//       pre:  hb[p^1] = h(t+1)
__global__ __launch_bounds__(512, 1) void kalman_ws3(
    const float* __restrict__ emis,   // [N]
    const float* __restrict__ Ht,     // [N,D]
    const float* __restrict__ Fg,     // [D,D]
    const float* __restrict__ Qg,     // [D,D]
    const float* __restrict__ Rg,     // [1]
    const float* __restrict__ mu0,    // [D]
    const float* __restrict__ Sigma0, // [D,D]
    float* __restrict__ out,          // [N,D]
    int n)
{
  __shared__ __align__(16) unsigned short PLhi[D * SB], PLlo[D * SB];   // P (sym, transposed store)
  __shared__ __align__(16) unsigned short M1Thi[D * SB], M1Tlo[D * SB]; // M1^T = F P
  __shared__ __align__(16) float hb_l[2][D];       // H row, double-buffered
  __shared__ __align__(16) float vv_l[D];          // v = P h (hi-precision part)
  __shared__ __align__(16) float Fmu_l[D];         // F @ mu   (init: mu0)
  __shared__ __align__(16) float wq_l[2][2][D];    // w row-half partials, double-buffered by parity
  __shared__ __align__(16) float sred_l[2];        // h.v partials (2 row-halves)
  __shared__ __align__(16) unsigned short muhi_l[D], mulo_l[D];  // mu bf16-split

  const int tid = threadIdx.x;
  const int l   = tid & 63;        // lane
  const int lg  = l >> 4;          // lane group (k-octet)
  const int lm  = l & 15;          // m/n within 16-tile
  const int wv  = tid >> 6;        // wave 0..7
  const int sq  = wv & 3;          // quadrant index (MFMA waves)
  const int R0  = (sq >> 1) * 32;  // quadrant row base
  const int C0  = (sq & 1) * 32;   // quadrant col base

  // ---------------- init ----------------
  for (int i = tid; i < D * D; i += 512) {
    const int rr = i >> 6, cc = i & 63;
    const float s = Sigma0[i];
    const unsigned b = fbits(s);
    PLhi[rr * SB + cc] = (unsigned short)(b >> 16);
    PLlo[rr * SB + cc] = (unsigned short)(fbits(s - bitsf(b & 0xFFFF0000u)) >> 16);
  }
  if (tid < D) {
    Fmu_l[tid] = mu0[tid];     // so mu(0) = Fmu + 0*w = mu0
    hb_l[0][tid] = Ht[tid];
    wq_l[1][0][tid] = 0.f;     // p^1 buffer at t=0
    wq_l[1][1][tid] = 0.f;
  }

  // F fragments in registers, kappa(lg,j)=8lg+j consistent for A and B (r3/r5/r6-verified)
  bf16x8 FBhi[2][2], FBlo[2][2], FAhi[2][2], FAlo[2][2];
  #pragma unroll
  for (int nt = 0; nt < 2; ++nt)
    #pragma unroll
    for (int kt = 0; kt < 2; ++kt) {
      split8t(&Fg[(C0 + 16 * nt + lm) * 64 + 8 * lg + 32 * kt], FBhi[nt][kt], FBlo[nt][kt]);
      split8t(&Fg[(R0 + 16 * nt + lm) * 64 + 8 * lg + 32 * kt], FAhi[nt][kt], FAlo[nt][kt]);
    }
  f32x4 Qc[2][2];
  #pragma unroll
  for (int mt = 0; mt < 2; ++mt)
    #pragma unroll
    for (int nt = 0; nt < 2; ++nt)
      #pragma unroll
      for (int j = 0; j < 4; ++j)
        Qc[mt][nt][j] = Qg[(R0 + 16 * mt + 4 * lg + j) * 64 + (C0 + 16 * nt + lm)];

  const float rp = Rg[0] + JITTER;
  __syncthreads();

  float y = 0.f, hn = 0.f, hmu = 0.f, muv = 0.f, kgp = 0.f;

  #pragma unroll 1
  for (int t = 0; t < n; ++t) {
    const int p = t & 1;

    // ======================= SEGMENT 1 =======================
    if (wv < 4) {
      const f32x4 hr0 = *(const f32x4*)&hb_l[p][R0 + 4 * lg];        // w-partial h rows, mt=0
      const f32x4 hr1 = *(const f32x4*)&hb_l[p][R0 + 16 + 4 * lg];   // mt=1
      // ---- A-frags ----
      bf16x8 Ahi[2][2], Alo[2][2];
      #pragma unroll
      for (int mt = 0; mt < 2; ++mt)
        #pragma unroll
        for (int kt = 0; kt < 2; ++kt) {
          const int off = (R0 + 16 * mt + lm) * SB + 8 * lg + 32 * kt;
          Ahi[mt][kt] = *(const bf16x8*)&PLhi[off];
          Alo[mt][kt] = *(const bf16x8*)&PLlo[off];
        }
      // ---- C0==32 pair: v = P_hi h from A-frags; S partials ----
      if (C0 == 32) {
        const f32x4 hk00 = *(const f32x4*)&hb_l[p][8 * lg];
        const f32x4 hk01 = *(const f32x4*)&hb_l[p][8 * lg + 4];
        const f32x4 hk10 = *(const f32x4*)&hb_l[p][32 + 8 * lg];
        const f32x4 hk11 = *(const f32x4*)&hb_l[p][32 + 8 * lg + 4];
        const float hs0 = hb_l[p][R0 + lm];
        const float hs1 = hb_l[p][R0 + 16 + lm];
        float vm0, vm1;
        #pragma unroll
        for (int mt = 0; mt < 2; ++mt) {
          float a0 = 0.f, a1 = 0.f;
          #pragma unroll
          for (int j = 0; j < 4; ++j) {
            a0 += bf2f(Ahi[mt][0][j])     * hk00[j];
            a0 += bf2f(Ahi[mt][0][j + 4]) * hk01[j];
            a1 += bf2f(Ahi[mt][1][j])     * hk10[j];
            a1 += bf2f(Ahi[mt][1][j + 4]) * hk11[j];
          }
          float vs = a0 + a1;
          vs += __shfl_xor(vs, 16);
          vs += __shfl_xor(vs, 32);
          if (mt == 0) vm0 = vs; else vm1 = vs;
        }
        if (l < 16) { vv_l[R0 + l] = vm0; vv_l[R0 + 16 + l] = vm1; }
        float sp = hs0 * vm0 + hs1 * vm1;
        sp += __shfl_xor(sp, 1);
        sp += __shfl_xor(sp, 2);
        sp += __shfl_xor(sp, 4);
        sp += __shfl_xor(sp, 8);
        if (l == 0) sred_l[R0 >> 5] = sp;
      }
      // ---- M1 = P @ F^T ----
      f32x4 acc1[2][2];
      #pragma unroll
      for (int mt = 0; mt < 2; ++mt)
        #pragma unroll
        for (int nt = 0; nt < 2; ++nt)
          acc1[mt][nt] = (f32x4){0.f, 0.f, 0.f, 0.f};
      #pragma unroll
      for (int kt = 0; kt < 2; ++kt)
        #pragma unroll
        for (int mt = 0; mt < 2; ++mt)
          #pragma unroll
          for (int nt = 0; nt < 2; ++nt) {
            acc1[mt][nt] = __builtin_amdgcn_mfma_f32_16x16x32_bf16(Ahi[mt][kt], FBhi[nt][kt], acc1[mt][nt], 0, 0, 0);
            acc1[mt][nt] = __builtin_amdgcn_mfma_f32_16x16x32_bf16(Ahi[mt][kt], FBlo[nt][kt], acc1[mt][nt], 0, 0, 0);
            acc1[mt][nt] = __builtin_amdgcn_mfma_f32_16x16x32_bf16(Alo[mt][kt], FBhi[nt][kt], acc1[mt][nt], 0, 0, 0);
          }
      // ---- w-partials: pw[nt] = sum_{r in R0-block} M1[r][C0+16nt+lm] h[r] ----
      float pw0 = 0.f, pw1 = 0.f;
      #pragma unroll
      for (int j = 0; j < 4; ++j) {
        pw0 += acc1[0][0][j] * hr0[j] + acc1[1][0][j] * hr1[j];
        pw1 += acc1[0][1][j] * hr0[j] + acc1[1][1][j] * hr1[j];
      }
      pw0 += __shfl_xor(pw0, 16); pw0 += __shfl_xor(pw0, 32);
      pw1 += __shfl_xor(pw1, 16); pw1 += __shfl_xor(pw1, 32);
      if (l < 16) {
        wq_l[p][R0 >> 5][C0 + lm]      = pw0;
        wq_l[p][R0 >> 5][C0 + 16 + lm] = pw1;
      }
      // ---- convert + store M1^T ----
      #pragma unroll
      for (int mt = 0; mt < 2; ++mt)
        #pragma unroll
        for (int nt = 0; nt < 2; ++nt) {
          const int idx = (C0 + 16 * nt + lm) * SB + R0 + 16 * mt + 4 * lg;
          uint2 h2, l2;
          split4(acc1[mt][nt], h2, l2);
          *reinterpret_cast<uint2*>(&M1Thi[idx]) = h2;
          *reinterpret_cast<uint2*>(&M1Tlo[idx]) = l2;
        }
    } else if (wv == 4) {
      // ---- aux: finalize mu(t); bf16-split store; hmu reduce; y ----
      y = emis[t];
      muv = Fmu_l[l] + kgp * (wq_l[p ^ 1][0][l] + wq_l[p ^ 1][1][l]);
      const unsigned b = fbits(muv);
      muhi_l[l] = (unsigned short)(b >> 16);
      mulo_l[l] = (unsigned short)(fbits(muv - bitsf(b & 0xFFFF0000u)) >> 16);
      float hm = hb_l[p][l] * muv;
      hm += __shfl_xor(hm, 1);
      hm += __shfl_xor(hm, 2);
      hm += __shfl_xor(hm, 4);
      hm += __shfl_xor(hm, 8);
      hm += __shfl_xor(hm, 16);
      hm += __shfl_xor(hm, 32);
      hmu = hm;
    } else if (wv == 5) {
      if (t + 1 < n) hn = Ht[(size_t)(t + 1) * D + l];
    }
    barrier_lds();   // B1: M1T, wq[p], vv, sred, muhi/mulo visible

    // ======================= SEGMENT 2 =======================
    if (wv < 4) {
      const float S = rp + sred_l[0] + sred_l[1];
      const float invS = 1.0f / S;
      // w pieces for the rank-1 term
      f32x4 wr0, wr1; float wc0, wc1;
      {
        const f32x4 a0 = *(const f32x4*)&wq_l[p][0][R0 + 4 * lg];
        const f32x4 b0 = *(const f32x4*)&wq_l[p][1][R0 + 4 * lg];
        const f32x4 a1 = *(const f32x4*)&wq_l[p][0][R0 + 16 + 4 * lg];
        const f32x4 b1 = *(const f32x4*)&wq_l[p][1][R0 + 16 + 4 * lg];
        #pragma unroll
        for (int j = 0; j < 4; ++j) { wr0[j] = a0[j] + b0[j]; wr1[j] = a1[j] + b1[j]; }
        wc0 = (wq_l[p][0][C0 + lm]      + wq_l[p][1][C0 + lm])      * invS;
        wc1 = (wq_l[p][0][C0 + 16 + lm] + wq_l[p][1][C0 + 16 + lm]) * invS;
      }
      f32x4 acc2[2][2];
      #pragma unroll
      for (int j = 0; j < 4; ++j) {
        acc2[0][0][j] = Qc[0][0][j] - wr0[j] * wc0;
        acc2[0][1][j] = Qc[0][1][j] - wr0[j] * wc1;
        acc2[1][0][j] = Qc[1][0][j] - wr1[j] * wc0;
        acc2[1][1][j] = Qc[1][1][j] - wr1[j] * wc1;
      }
      #pragma unroll
      for (int kt = 0; kt < 2; ++kt) {
        bf16x8 Bhi[2], Blo[2];
        #pragma unroll
        for (int nt = 0; nt < 2; ++nt) {
          const int off = (C0 + 16 * nt + lm) * SB + 8 * lg + 32 * kt;
          Bhi[nt] = *(const bf16x8*)&M1Thi[off];
          Blo[nt] = *(const bf16x8*)&M1Tlo[off];
        }
        #pragma unroll
        for (int mt = 0; mt < 2; ++mt)
          #pragma unroll
          for (int nt = 0; nt < 2; ++nt) {
            acc2[mt][nt] = __builtin_amdgcn_mfma_f32_16x16x32_bf16(FAhi[mt][kt], Bhi[nt], acc2[mt][nt], 0, 0, 0);
            acc2[mt][nt] = __builtin_amdgcn_mfma_f32_16x16x32_bf16(FAhi[mt][kt], Blo[nt], acc2[mt][nt], 0, 0, 0);
            acc2[mt][nt] = __builtin_amdgcn_mfma_f32_16x16x32_bf16(FAlo[mt][kt], Bhi[nt], acc2[mt][nt], 0, 0, 0);
          }
      }
      // ---- C0==0 pair: Fmu = F @ mu as an extra B column ----
      if (C0 == 0) {
        f32x4 accm0 = (f32x4){0.f,0.f,0.f,0.f}, accm1 = (f32x4){0.f,0.f,0.f,0.f};
        #pragma unroll
        for (int kt = 0; kt < 2; ++kt) {
          bf16x8 mh = *(const bf16x8*)&muhi_l[32 * kt + 8 * lg];
          bf16x8 ml = *(const bf16x8*)&mulo_l[32 * kt + 8 * lg];
          if (lm != 0) { mh = (bf16x8)(short)0; ml = (bf16x8)(short)0; }
          accm0 = __builtin_amdgcn_mfma_f32_16x16x32_bf16(FAhi[0][kt], mh, accm0, 0, 0, 0);
          accm0 = __builtin_amdgcn_mfma_f32_16x16x32_bf16(FAhi[0][kt], ml, accm0, 0, 0, 0);
          accm0 = __builtin_amdgcn_mfma_f32_16x16x32_bf16(FAlo[0][kt], mh, accm0, 0, 0, 0);
          accm1 = __builtin_amdgcn_mfma_f32_16x16x32_bf16(FAhi[1][kt], mh, accm1, 0, 0, 0);
          accm1 = __builtin_amdgcn_mfma_f32_16x16x32_bf16(FAhi[1][kt], ml, accm1, 0, 0, 0);
          accm1 = __builtin_amdgcn_mfma_f32_16x16x32_bf16(FAlo[1][kt], mh, accm1, 0, 0, 0);
        }
        if (lm == 0) {
          *(f32x4*)&Fmu_l[R0 + 4 * lg]      = accm0;
          *(f32x4*)&Fmu_l[R0 + 16 + 4 * lg] = accm1;
        }
      }
      // ---- store P' transposed (== P', symmetric) ----
      #pragma unroll
      for (int mt = 0; mt < 2; ++mt)
        #pragma unroll
        for (int nt = 0; nt < 2; ++nt) {
          const int idx = (C0 + 16 * nt + lm) * SB + R0 + 16 * mt + 4 * lg;
          uint2 h2, l2;
          split4(acc2[mt][nt], h2, l2);
          *reinterpret_cast<uint2*>(&PLhi[idx]) = h2;
          *reinterpret_cast<uint2*>(&PLlo[idx]) = l2;
        }
    } else if (wv == 4) {
      const float S = rp + sred_l[0] + sred_l[1];
      const float kg = (y - hmu) / S;
      out[(size_t)t * D + l] = muv + kg * vv_l[l];
      kgp = kg;
    } else if (wv == 5) {
      if (t + 1 < n) hb_l[p ^ 1][l] = hn;
    }
    barrier_lds();   // B2: P', Fmu, h ready for next step
  }
}

extern "C" void kernel_launch(void* const* d_in, const int* in_sizes, int n_in,
                              void* d_out, int out_size, void* d_ws, size_t ws_size,
                              hipStream_t stream) {
  (void)n_in; (void)d_ws; (void)ws_size; (void)out_size;
  const float* emis   = (const float*)d_in[0];
  const float* Ht     = (const float*)d_in[1];
  const float* F      = (const float*)d_in[2];
  const float* Q      = (const float*)d_in[3];
  const float* R      = (const float*)d_in[4];
  const float* mu0    = (const float*)d_in[5];
  const float* Sigma0 = (const float*)d_in[6];
  float* out = (float*)d_out;
  const int n = in_sizes[0];
  hipLaunchKernelGGL(kalman_ws3, dim3(1), dim3(512), 0, stream,
                     emis, Ht, F, Q, R, mu0, Sigma0, out, n);
}

// Round 8
// 115216.125 us; speedup vs baseline: 1.1082x; 1.1082x over previous
//
#include <hip/hip_runtime.h>
#include <cstddef>

typedef float f32x4 __attribute__((ext_vector_type(4)));
typedef short bf16x8 __attribute__((ext_vector_type(8)));

namespace {
constexpr int D = 64;
constexpr int SB = 72;   // bf16 LDS row stride (shorts)
constexpr float JITTER = 1e-6f;
}

__device__ __forceinline__ unsigned fbits(float x){ union{float f;unsigned u;}v; v.f=x; return v.u; }
__device__ __forceinline__ float bitsf(unsigned u){ union{unsigned u;float f;}v; v.u=u; return v.f; }
__device__ __forceinline__ float bf2f(short h){ return bitsf(((unsigned)(unsigned short)h)<<16); }

__device__ __forceinline__ void split4(const f32x4 dv, uint2& hi, uint2& lo) {
  const unsigned b0 = fbits(dv[0]), b1 = fbits(dv[1]), b2 = fbits(dv[2]), b3 = fbits(dv[3]);
  hi.x = __builtin_amdgcn_perm(b1, b0, 0x07060302u);
  hi.y = __builtin_amdgcn_perm(b3, b2, 0x07060302u);
  const float r0 = dv[0] - bitsf(b0 & 0xFFFF0000u);
  const float r1 = dv[1] - bitsf(b1 & 0xFFFF0000u);
  const float r2 = dv[2] - bitsf(b2 & 0xFFFF0000u);
  const float r3 = dv[3] - bitsf(b3 & 0xFFFF0000u);
  lo.x = __builtin_amdgcn_perm(fbits(r1), fbits(r0), 0x07060302u);
  lo.y = __builtin_amdgcn_perm(fbits(r3), fbits(r2), 0x07060302u);
}

__device__ __forceinline__ void split8t(const float* src, bf16x8& hi, bf16x8& lo) {
  #pragma unroll
  for (int j = 0; j < 8; ++j) {
    const unsigned b = fbits(src[j]);
    hi[j] = (short)(b >> 16);
    const float r = src[j] - bitsf(b & 0xFFFF0000u);
    lo[j] = (short)(fbits(r) >> 16);
  }
}

// Barrier without the vmcnt(0) drain (LDS ordering only).
__device__ __forceinline__ void barrier_lds() {
  asm volatile("s_waitcnt lgkmcnt(0)\n\ts_barrier" ::: "memory");
}

// 8 waves: 0-3 MFMA (2x2 quadrants of 64x64), 4 = aux, 5 = prefetch, 6-7 idle.
// 2 barriers/step:
// seg1: MFMA waves: M1 = P@F^T (24 mfma); C0==0 pair: v = P h from A-frags (+S
//       partials); C0==32 pair: Fmu = F@mu from FA-frags; all: w-partials from
//       acc1, M1T bf16 store.   aux: y, hmu = h.mu.   pre: load h(t+1).
// seg2: MFMA waves: acc2 = Q - w w^T/S + F@M1 (24 mfma); P' store.
//       aux: kg; out = mu + kg v; mu' = Fmu + kg w.   pre: hb[p^1] = h(t+1).
__global__ __launch_bounds__(512, 1) void kalman_ws4(
    const float* __restrict__ emis,   // [N]
    const float* __restrict__ Ht,     // [N,D]
    const float* __restrict__ Fg,     // [D,D]
    const float* __restrict__ Qg,     // [D,D]
    const float* __restrict__ Rg,     // [1]
    const float* __restrict__ mu0,    // [D]
    const float* __restrict__ Sigma0, // [D,D]
    float* __restrict__ out,          // [N,D]
    int n)
{
  __shared__ __align__(16) unsigned short PLhi[D * SB], PLlo[D * SB];   // P (sym, transposed store)
  __shared__ __align__(16) unsigned short M1Thi[D * SB], M1Tlo[D * SB]; // M1^T = F P
  __shared__ __align__(16) float hb_l[2][D];    // H row, double-buffered
  __shared__ __align__(16) float mu_l[2][D];    // predicted mean, double-buffered
  __shared__ __align__(16) float vv_l[D];       // v = P h
  __shared__ __align__(16) float Fmu_l[D];      // F @ mu
  __shared__ __align__(16) float wq_l[2][D];    // w row-half partials (w = M1^T h)
  __shared__ __align__(16) float sred_l[2];     // h.v partials (2 row-halves)

  const int tid = threadIdx.x;
  const int l   = tid & 63;        // lane
  const int lg  = l >> 4;          // lane group (k-octet)
  const int lm  = l & 15;          // m/n within 16-tile
  const int wv  = tid >> 6;        // wave 0..7
  const int sq  = wv & 3;          // quadrant index (MFMA waves)
  const int R0  = (sq >> 1) * 32;  // quadrant row base
  const int C0  = (sq & 1) * 32;   // quadrant col base

  // ---------------- init ----------------
  for (int i = tid; i < D * D; i += 512) {
    const int rr = i >> 6, cc = i & 63;
    const float s = Sigma0[i];
    const unsigned b = fbits(s);
    PLhi[rr * SB + cc] = (unsigned short)(b >> 16);
    PLlo[rr * SB + cc] = (unsigned short)(fbits(s - bitsf(b & 0xFFFF0000u)) >> 16);
  }
  if (tid < D) {
    mu_l[0][tid] = mu0[tid];
    hb_l[0][tid] = Ht[tid];
  }

  // F fragments in registers, kappa(lg,j)=8lg+j consistent for A and B (r3/r5/r6-verified)
  bf16x8 FBhi[2][2], FBlo[2][2], FAhi[2][2], FAlo[2][2];
  #pragma unroll
  for (int nt = 0; nt < 2; ++nt)
    #pragma unroll
    for (int kt = 0; kt < 2; ++kt) {
      split8t(&Fg[(C0 + 16 * nt + lm) * 64 + 8 * lg + 32 * kt], FBhi[nt][kt], FBlo[nt][kt]);
      split8t(&Fg[(R0 + 16 * nt + lm) * 64 + 8 * lg + 32 * kt], FAhi[nt][kt], FAlo[nt][kt]);
    }
  f32x4 Qc[2][2];
  #pragma unroll
  for (int mt = 0; mt < 2; ++mt)
    #pragma unroll
    for (int nt = 0; nt < 2; ++nt)
      #pragma unroll
      for (int j = 0; j < 4; ++j)
        Qc[mt][nt][j] = Qg[(R0 + 16 * mt + 4 * lg + j) * 64 + (C0 + 16 * nt + lm)];

  const float rp = Rg[0] + JITTER;
  __syncthreads();

  float y = 0.f, hn = 0.f, hmu = 0.f;

  #pragma unroll 1
  for (int t = 0; t < n; ++t) {
    const int p = t & 1;

    // ======================= SEGMENT 1 =======================
    if (wv < 4) {
      // ---- A-frags (P quadrant, hi+lo) ----
      bf16x8 Ahi[2][2], Alo[2][2];
      #pragma unroll
      for (int mt = 0; mt < 2; ++mt)
        #pragma unroll
        for (int kt = 0; kt < 2; ++kt) {
          const int off = (R0 + 16 * mt + lm) * SB + 8 * lg + 32 * kt;
          Ahi[mt][kt] = *(const bf16x8*)&PLhi[off];
          Alo[mt][kt] = *(const bf16x8*)&PLlo[off];
        }
      // ---- M1 = P @ F^T (24 mfma) ----
      f32x4 acc1[2][2];
      #pragma unroll
      for (int mt = 0; mt < 2; ++mt)
        #pragma unroll
        for (int nt = 0; nt < 2; ++nt)
          acc1[mt][nt] = (f32x4){0.f, 0.f, 0.f, 0.f};
      #pragma unroll
      for (int kt = 0; kt < 2; ++kt)
        #pragma unroll
        for (int mt = 0; mt < 2; ++mt)
          #pragma unroll
          for (int nt = 0; nt < 2; ++nt) {
            acc1[mt][nt] = __builtin_amdgcn_mfma_f32_16x16x32_bf16(Ahi[mt][kt], FBhi[nt][kt], acc1[mt][nt], 0, 0, 0);
            acc1[mt][nt] = __builtin_amdgcn_mfma_f32_16x16x32_bf16(Ahi[mt][kt], FBlo[nt][kt], acc1[mt][nt], 0, 0, 0);
            acc1[mt][nt] = __builtin_amdgcn_mfma_f32_16x16x32_bf16(Alo[mt][kt], FBhi[nt][kt], acc1[mt][nt], 0, 0, 0);
          }

      // ---- per-pair extra VALU (overlaps MFMA drain; balanced across pairs) ----
      if ((sq & 1) == 0) {
        // v = P h for rows R0..R0+31 (hi+lo precision), + h.v partial
        const f32x4 hk0a = *(const f32x4*)&hb_l[p][8 * lg];
        const f32x4 hk0b = *(const f32x4*)&hb_l[p][8 * lg + 4];
        const f32x4 hk1a = *(const f32x4*)&hb_l[p][32 + 8 * lg];
        const f32x4 hk1b = *(const f32x4*)&hb_l[p][32 + 8 * lg + 4];
        float pv0 = 0.f, pv1 = 0.f;
        #pragma unroll
        for (int j = 0; j < 4; ++j) {
          pv0 += (bf2f(Ahi[0][0][j])     + bf2f(Alo[0][0][j]))     * hk0a[j];
          pv0 += (bf2f(Ahi[0][0][j + 4]) + bf2f(Alo[0][0][j + 4])) * hk0b[j];
          pv0 += (bf2f(Ahi[0][1][j])     + bf2f(Alo[0][1][j]))     * hk1a[j];
          pv0 += (bf2f(Ahi[0][1][j + 4]) + bf2f(Alo[0][1][j + 4])) * hk1b[j];
          pv1 += (bf2f(Ahi[1][0][j])     + bf2f(Alo[1][0][j]))     * hk0a[j];
          pv1 += (bf2f(Ahi[1][0][j + 4]) + bf2f(Alo[1][0][j + 4])) * hk0b[j];
          pv1 += (bf2f(Ahi[1][1][j])     + bf2f(Alo[1][1][j]))     * hk1a[j];
          pv1 += (bf2f(Ahi[1][1][j + 4]) + bf2f(Alo[1][1][j + 4])) * hk1b[j];
        }
        pv0 += __shfl_xor(pv0, 16); pv0 += __shfl_xor(pv0, 32);
        pv1 += __shfl_xor(pv1, 16); pv1 += __shfl_xor(pv1, 32);
        if (l < 16) { vv_l[R0 + lm] = pv0; vv_l[R0 + 16 + lm] = pv1; }
        float sp = hb_l[p][R0 + lm] * pv0 + hb_l[p][R0 + 16 + lm] * pv1;
        sp += __shfl_xor(sp, 1);
        sp += __shfl_xor(sp, 2);
        sp += __shfl_xor(sp, 4);
        sp += __shfl_xor(sp, 8);
        if (l == 0) sred_l[R0 >> 5] = sp;
      } else {
        // Fmu = F @ mu for rows R0..R0+31 from FA-frags
        const f32x4 mk0a = *(const f32x4*)&mu_l[p][8 * lg];
        const f32x4 mk0b = *(const f32x4*)&mu_l[p][8 * lg + 4];
        const f32x4 mk1a = *(const f32x4*)&mu_l[p][32 + 8 * lg];
        const f32x4 mk1b = *(const f32x4*)&mu_l[p][32 + 8 * lg + 4];
        float pm0 = 0.f, pm1 = 0.f;
        #pragma unroll
        for (int j = 0; j < 4; ++j) {
          pm0 += (bf2f(FAhi[0][0][j])     + bf2f(FAlo[0][0][j]))     * mk0a[j];
          pm0 += (bf2f(FAhi[0][0][j + 4]) + bf2f(FAlo[0][0][j + 4])) * mk0b[j];
          pm0 += (bf2f(FAhi[0][1][j])     + bf2f(FAlo[0][1][j]))     * mk1a[j];
          pm0 += (bf2f(FAhi[0][1][j + 4]) + bf2f(FAlo[0][1][j + 4])) * mk1b[j];
          pm1 += (bf2f(FAhi[1][0][j])     + bf2f(FAlo[1][0][j]))     * mk0a[j];
          pm1 += (bf2f(FAhi[1][0][j + 4]) + bf2f(FAlo[1][0][j + 4])) * mk0b[j];
          pm1 += (bf2f(FAhi[1][1][j])     + bf2f(FAlo[1][1][j]))     * mk1a[j];
          pm1 += (bf2f(FAhi[1][1][j + 4]) + bf2f(FAlo[1][1][j + 4])) * mk1b[j];
        }
        pm0 += __shfl_xor(pm0, 16); pm0 += __shfl_xor(pm0, 32);
        pm1 += __shfl_xor(pm1, 16); pm1 += __shfl_xor(pm1, 32);
        if (l < 16) { Fmu_l[R0 + lm] = pm0; Fmu_l[R0 + 16 + lm] = pm1; }
      }

      // ---- w-partials from acc1: pw[nt] = sum_{rows in R0-block} M1[r][C0+16nt+lm] h[r] ----
      {
        const f32x4 hr0 = *(const f32x4*)&hb_l[p][R0 + 4 * lg];
        const f32x4 hr1 = *(const f32x4*)&hb_l[p][R0 + 16 + 4 * lg];
        float pw0 = 0.f, pw1 = 0.f;
        #pragma unroll
        for (int j = 0; j < 4; ++j) {
          pw0 += acc1[0][0][j] * hr0[j] + acc1[1][0][j] * hr1[j];
          pw1 += acc1[0][1][j] * hr0[j] + acc1[1][1][j] * hr1[j];
        }
        pw0 += __shfl_xor(pw0, 16); pw0 += __shfl_xor(pw0, 32);
        pw1 += __shfl_xor(pw1, 16); pw1 += __shfl_xor(pw1, 32);
        if (l < 16) {
          wq_l[R0 >> 5][C0 + lm]      = pw0;
          wq_l[R0 >> 5][C0 + 16 + lm] = pw1;
        }
      }
      // ---- convert + store M1^T ----
      #pragma unroll
      for (int mt = 0; mt < 2; ++mt)
        #pragma unroll
        for (int nt = 0; nt < 2; ++nt) {
          const int idx = (C0 + 16 * nt + lm) * SB + R0 + 16 * mt + 4 * lg;
          uint2 h2, l2;
          split4(acc1[mt][nt], h2, l2);
          *reinterpret_cast<uint2*>(&M1Thi[idx]) = h2;
          *reinterpret_cast<uint2*>(&M1Tlo[idx]) = l2;
        }
    } else if (wv == 4) {
      // ---- aux: y, hmu = h.mu ----
      y = emis[t];
      float hm = hb_l[p][l] * mu_l[p][l];
      hm += __shfl_xor(hm, 1);
      hm += __shfl_xor(hm, 2);
      hm += __shfl_xor(hm, 4);
      hm += __shfl_xor(hm, 8);
      hm += __shfl_xor(hm, 16);
      hm += __shfl_xor(hm, 32);
      hmu = hm;
    } else if (wv == 5) {
      if (t + 1 < n) hn = Ht[(size_t)(t + 1) * D + l];
    }
    barrier_lds();   // B1: M1T, wq, vv, Fmu, sred visible

    // ======================= SEGMENT 2 =======================
    if (wv < 4) {
      const float S = rp + sred_l[0] + sred_l[1];
      const float invS = 1.0f / S;
      // w pieces for the rank-1 term
      f32x4 wr0, wr1; float wc0, wc1;
      {
        const f32x4 a0 = *(const f32x4*)&wq_l[0][R0 + 4 * lg];
        const f32x4 b0 = *(const f32x4*)&wq_l[1][R0 + 4 * lg];
        const f32x4 a1 = *(const f32x4*)&wq_l[0][R0 + 16 + 4 * lg];
        const f32x4 b1 = *(const f32x4*)&wq_l[1][R0 + 16 + 4 * lg];
        #pragma unroll
        for (int j = 0; j < 4; ++j) { wr0[j] = a0[j] + b0[j]; wr1[j] = a1[j] + b1[j]; }
        wc0 = (wq_l[0][C0 + lm]      + wq_l[1][C0 + lm])      * invS;
        wc1 = (wq_l[0][C0 + 16 + lm] + wq_l[1][C0 + 16 + lm]) * invS;
      }
      f32x4 acc2[2][2];
      #pragma unroll
      for (int j = 0; j < 4; ++j) {
        acc2[0][0][j] = Qc[0][0][j] - wr0[j] * wc0;
        acc2[0][1][j] = Qc[0][1][j] - wr0[j] * wc1;
        acc2[1][0][j] = Qc[1][0][j] - wr1[j] * wc0;
        acc2[1][1][j] = Qc[1][1][j] - wr1[j] * wc1;
      }
      #pragma unroll
      for (int kt = 0; kt < 2; ++kt) {
        bf16x8 Bhi[2], Blo[2];
        #pragma unroll
        for (int nt = 0; nt < 2; ++nt) {
          const int off = (C0 + 16 * nt + lm) * SB + 8 * lg + 32 * kt;
          Bhi[nt] = *(const bf16x8*)&M1Thi[off];
          Blo[nt] = *(const bf16x8*)&M1Tlo[off];
        }
        #pragma unroll
        for (int mt = 0; mt < 2; ++mt)
          #pragma unroll
          for (int nt = 0; nt < 2; ++nt) {
            acc2[mt][nt] = __builtin_amdgcn_mfma_f32_16x16x32_bf16(FAhi[mt][kt], Bhi[nt], acc2[mt][nt], 0, 0, 0);
            acc2[mt][nt] = __builtin_amdgcn_mfma_f32_16x16x32_bf16(FAhi[mt][kt], Blo[nt], acc2[mt][nt], 0, 0, 0);
            acc2[mt][nt] = __builtin_amdgcn_mfma_f32_16x16x32_bf16(FAlo[mt][kt], Bhi[nt], acc2[mt][nt], 0, 0, 0);
          }
      }
      // ---- store P' transposed (== P', symmetric) ----
      #pragma unroll
      for (int mt = 0; mt < 2; ++mt)
        #pragma unroll
        for (int nt = 0; nt < 2; ++nt) {
          const int idx = (C0 + 16 * nt + lm) * SB + R0 + 16 * mt + 4 * lg;
          uint2 h2, l2;
          split4(acc2[mt][nt], h2, l2);
          *reinterpret_cast<uint2*>(&PLhi[idx]) = h2;
          *reinterpret_cast<uint2*>(&PLlo[idx]) = l2;
        }
    } else if (wv == 4) {
      const float S = rp + sred_l[0] + sred_l[1];
      const float kg = (y - hmu) / S;
      out[(size_t)t * D + l] = mu_l[p][l] + kg * vv_l[l];
      mu_l[p ^ 1][l] = Fmu_l[l] + kg * (wq_l[0][l] + wq_l[1][l]);
    } else if (wv == 5) {
      if (t + 1 < n) hb_l[p ^ 1][l] = hn;
    }
    barrier_lds();   // B2: P', mu', h ready for next step
  }
}

extern "C" void kernel_launch(void* const* d_in, const int* in_sizes, int n_in,
                              void* d_out, int out_size, void* d_ws, size_t ws_size,
                              hipStream_t stream) {
  (void)n_in; (void)d_ws; (void)ws_size; (void)out_size;
  const float* emis   = (const float*)d_in[0];
  const float* Ht     = (const float*)d_in[1];
  const float* F      = (const float*)d_in[2];
  const float* Q      = (const float*)d_in[3];
  const float* R      = (const float*)d_in[4];
  const float* mu0    = (const float*)d_in[5];
  const float* Sigma0 = (const float*)d_in[6];
  float* out = (float*)d_out;
  const int n = in_sizes[0];
  hipLaunchKernelGGL(kalman_ws4, dim3(1), dim3(512), 0, stream,
                     emis, Ht, F, Q, R, mu0, Sigma0, out, n);
}

// Round 9
// 85007.129 us; speedup vs baseline: 1.5020x; 1.3554x over previous
//
#include <hip/hip_runtime.h>
#include <cstddef>

typedef float f32x4 __attribute__((ext_vector_type(4)));
typedef _Float16 f16x8 __attribute__((ext_vector_type(8)));
typedef _Float16 f16x4 __attribute__((ext_vector_type(4)));

namespace {
constexpr int D = 64;
constexpr int SB = 72;   // f16 LDS row stride (elements); 144 B rows
constexpr float JITTER = 1e-6f;
constexpr float LO_SCALE = 1024.0f;   // keeps F lo-residuals in fp16 normal range
constexpr float LO_INV   = 1.0f / 1024.0f;
}

// Barrier without the vmcnt(0) drain (LDS ordering only); out-store/prefetch
// carry no cross-wave dependency.
__device__ __forceinline__ void barrier_lds() {
  asm volatile("s_waitcnt lgkmcnt(0)\n\ts_barrier" ::: "memory");
}

__device__ __forceinline__ f16x4 pack4(const f32x4 dv) {
  f16x4 r;
  r[0] = (_Float16)dv[0]; r[1] = (_Float16)dv[1];
  r[2] = (_Float16)dv[2]; r[3] = (_Float16)dv[3];
  return r;
}

// split 8 f32 into f16 hi + 2^10-scaled f16 residual (init-only, for F frags)
__device__ __forceinline__ void split8f(const float* src, f16x8& hi, f16x8& lo) {
  #pragma unroll
  for (int j = 0; j < 8; ++j) {
    const _Float16 h = (_Float16)src[j];
    hi[j] = h;
    lo[j] = (_Float16)((src[j] - (float)h) * LO_SCALE);
  }
}

// 8 waves: 0-3 MFMA (2x2 quadrants of 64x64), 4 = aux, 5 = prefetch, 6-7 idle.
// P, M1 stored single-fp16; F in registers as fp16 hi + scaled-lo pair.
// 2 barriers/step:
// seg1: MFMA waves: M1 = P@F^T (16 mfma hi + lo-pass fold); C0==0 pair: v = P h
//       from A-frags (+S partials); C0==32 pair: Fmu = F@mu from FA-frags;
//       all: w-partials from acc1, M1T f16 store.  aux: y, hmu.  pre: h(t+1).
// seg2: MFMA waves: acc2 = Q - w w^T/S + F@M1 (16+16 mfma); P' store.
//       aux: kg; out = mu + kg v; mu' = Fmu + kg w.  pre: hb[p^1] = h(t+1).
__global__ __launch_bounds__(512, 1) void kalman_f16(
    const float* __restrict__ emis,   // [N]
    const float* __restrict__ Ht,     // [N,D]
    const float* __restrict__ Fg,     // [D,D]
    const float* __restrict__ Qg,     // [D,D]
    const float* __restrict__ Rg,     // [1]
    const float* __restrict__ mu0,    // [D]
    const float* __restrict__ Sigma0, // [D,D]
    float* __restrict__ out,          // [N,D]
    int n)
{
  __shared__ __align__(16) _Float16 PL[D * SB];    // P (sym, transposed store), single fp16
  __shared__ __align__(16) _Float16 M1T[D * SB];   // M1^T = F P, single fp16
  __shared__ __align__(16) float hb_l[2][D];    // H row, double-buffered
  __shared__ __align__(16) float mu_l[2][D];    // predicted mean, double-buffered
  __shared__ __align__(16) float vv_l[D];       // v = P h
  __shared__ __align__(16) float Fmu_l[D];      // F @ mu
  __shared__ __align__(16) float wq_l[2][D];    // w row-half partials (w = M1^T h)
  __shared__ __align__(16) float sred_l[2];     // h.v partials (2 row-halves)

  const int tid = threadIdx.x;
  const int l   = tid & 63;        // lane
  const int lg  = l >> 4;          // lane group (k-octet)
  const int lm  = l & 15;          // m/n within 16-tile
  const int wv  = tid >> 6;        // wave 0..7
  const int sq  = wv & 3;          // quadrant index (MFMA waves)
  const int R0  = (sq >> 1) * 32;  // quadrant row base
  const int C0  = (sq & 1) * 32;   // quadrant col base

  // ---------------- init ----------------
  for (int i = tid; i < D * D; i += 512) {
    const int rr = i >> 6, cc = i & 63;
    PL[rr * SB + cc] = (_Float16)Sigma0[i];
  }
  if (tid < D) {
    mu_l[0][tid] = mu0[tid];
    hb_l[0][tid] = Ht[tid];
  }

  // F fragments in registers (fp16 hi + scaled lo), kappa(lg,j)=8lg+j
  // consistent for A and B (layout verified r3..r8):
  f16x8 FBhi[2][2], FBlo[2][2], FAhi[2][2], FAlo[2][2];
  #pragma unroll
  for (int nt = 0; nt < 2; ++nt)
    #pragma unroll
    for (int kt = 0; kt < 2; ++kt) {
      split8f(&Fg[(C0 + 16 * nt + lm) * 64 + 8 * lg + 32 * kt], FBhi[nt][kt], FBlo[nt][kt]);
      split8f(&Fg[(R0 + 16 * nt + lm) * 64 + 8 * lg + 32 * kt], FAhi[nt][kt], FAlo[nt][kt]);
    }
  f32x4 Qc[2][2];
  #pragma unroll
  for (int mt = 0; mt < 2; ++mt)
    #pragma unroll
    for (int nt = 0; nt < 2; ++nt)
      #pragma unroll
      for (int j = 0; j < 4; ++j)
        Qc[mt][nt][j] = Qg[(R0 + 16 * mt + 4 * lg + j) * 64 + (C0 + 16 * nt + lm)];

  const float rp = Rg[0] + JITTER;
  __syncthreads();

  float y = 0.f, hn = 0.f, hmu = 0.f;

  #pragma unroll 1
  for (int t = 0; t < n; ++t) {
    const int p = t & 1;

    // ======================= SEGMENT 1 =======================
    if (wv < 4) {
      // ---- A-frags (P quadrant, single fp16) ----
      f16x8 Af[2][2];
      #pragma unroll
      for (int mt = 0; mt < 2; ++mt)
        #pragma unroll
        for (int kt = 0; kt < 2; ++kt)
          Af[mt][kt] = *(const f16x8*)&PL[(R0 + 16 * mt + lm) * SB + 8 * lg + 32 * kt];

      // ---- M1 = P @ F^T : hi-pass + scaled-lo-pass, fold ----
      f32x4 acc1[2][2], acc1lo[2][2];
      #pragma unroll
      for (int mt = 0; mt < 2; ++mt)
        #pragma unroll
        for (int nt = 0; nt < 2; ++nt) {
          acc1[mt][nt]   = (f32x4){0.f, 0.f, 0.f, 0.f};
          acc1lo[mt][nt] = (f32x4){0.f, 0.f, 0.f, 0.f};
        }
      #pragma unroll
      for (int kt = 0; kt < 2; ++kt)
        #pragma unroll
        for (int mt = 0; mt < 2; ++mt)
          #pragma unroll
          for (int nt = 0; nt < 2; ++nt) {
            acc1[mt][nt]   = __builtin_amdgcn_mfma_f32_16x16x32_f16(Af[mt][kt], FBhi[nt][kt], acc1[mt][nt],   0, 0, 0);
            acc1lo[mt][nt] = __builtin_amdgcn_mfma_f32_16x16x32_f16(Af[mt][kt], FBlo[nt][kt], acc1lo[mt][nt], 0, 0, 0);
          }
      #pragma unroll
      for (int mt = 0; mt < 2; ++mt)
        #pragma unroll
        for (int nt = 0; nt < 2; ++nt)
          #pragma unroll
          for (int j = 0; j < 4; ++j)
            acc1[mt][nt][j] += acc1lo[mt][nt][j] * LO_INV;

      // ---- per-pair side compute (overlaps MFMA drain) ----
      if ((sq & 1) == 0) {
        // v = P h for rows R0..R0+31 from A-frags, + h.v partial
        const f32x4 hk0a = *(const f32x4*)&hb_l[p][8 * lg];
        const f32x4 hk0b = *(const f32x4*)&hb_l[p][8 * lg + 4];
        const f32x4 hk1a = *(const f32x4*)&hb_l[p][32 + 8 * lg];
        const f32x4 hk1b = *(const f32x4*)&hb_l[p][32 + 8 * lg + 4];
        float pv0 = 0.f, pv1 = 0.f;
        #pragma unroll
        for (int j = 0; j < 4; ++j) {
          pv0 += (float)Af[0][0][j]     * hk0a[j];
          pv0 += (float)Af[0][0][j + 4] * hk0b[j];
          pv0 += (float)Af[0][1][j]     * hk1a[j];
          pv0 += (float)Af[0][1][j + 4] * hk1b[j];
          pv1 += (float)Af[1][0][j]     * hk0a[j];
          pv1 += (float)Af[1][0][j + 4] * hk0b[j];
          pv1 += (float)Af[1][1][j]     * hk1a[j];
          pv1 += (float)Af[1][1][j + 4] * hk1b[j];
        }
        pv0 += __shfl_xor(pv0, 16); pv0 += __shfl_xor(pv0, 32);
        pv1 += __shfl_xor(pv1, 16); pv1 += __shfl_xor(pv1, 32);
        if (l < 16) { vv_l[R0 + lm] = pv0; vv_l[R0 + 16 + lm] = pv1; }
        float sp = hb_l[p][R0 + lm] * pv0 + hb_l[p][R0 + 16 + lm] * pv1;
        sp += __shfl_xor(sp, 1);
        sp += __shfl_xor(sp, 2);
        sp += __shfl_xor(sp, 4);
        sp += __shfl_xor(sp, 8);
        if (l == 0) sred_l[R0 >> 5] = sp;
      } else {
        // Fmu = F @ mu for rows R0..R0+31 from FA-hi frags
        const f32x4 mk0a = *(const f32x4*)&mu_l[p][8 * lg];
        const f32x4 mk0b = *(const f32x4*)&mu_l[p][8 * lg + 4];
        const f32x4 mk1a = *(const f32x4*)&mu_l[p][32 + 8 * lg];
        const f32x4 mk1b = *(const f32x4*)&mu_l[p][32 + 8 * lg + 4];
        float pm0 = 0.f, pm1 = 0.f;
        #pragma unroll
        for (int j = 0; j < 4; ++j) {
          pm0 += (float)FAhi[0][0][j]     * mk0a[j];
          pm0 += (float)FAhi[0][0][j + 4] * mk0b[j];
          pm0 += (float)FAhi[0][1][j]     * mk1a[j];
          pm0 += (float)FAhi[0][1][j + 4] * mk1b[j];
          pm1 += (float)FAhi[1][0][j]     * mk0a[j];
          pm1 += (float)FAhi[1][0][j + 4] * mk0b[j];
          pm1 += (float)FAhi[1][1][j]     * mk1a[j];
          pm1 += (float)FAhi[1][1][j + 4] * mk1b[j];
        }
        pm0 += __shfl_xor(pm0, 16); pm0 += __shfl_xor(pm0, 32);
        pm1 += __shfl_xor(pm1, 16); pm1 += __shfl_xor(pm1, 32);
        if (l < 16) { Fmu_l[R0 + lm] = pm0; Fmu_l[R0 + 16 + lm] = pm1; }
      }

      // ---- w-partials from folded acc1 ----
      {
        const f32x4 hr0 = *(const f32x4*)&hb_l[p][R0 + 4 * lg];
        const f32x4 hr1 = *(const f32x4*)&hb_l[p][R0 + 16 + 4 * lg];
        float pw0 = 0.f, pw1 = 0.f;
        #pragma unroll
        for (int j = 0; j < 4; ++j) {
          pw0 += acc1[0][0][j] * hr0[j] + acc1[1][0][j] * hr1[j];
          pw1 += acc1[0][1][j] * hr0[j] + acc1[1][1][j] * hr1[j];
        }
        pw0 += __shfl_xor(pw0, 16); pw0 += __shfl_xor(pw0, 32);
        pw1 += __shfl_xor(pw1, 16); pw1 += __shfl_xor(pw1, 32);
        if (l < 16) {
          wq_l[R0 >> 5][C0 + lm]      = pw0;
          wq_l[R0 >> 5][C0 + 16 + lm] = pw1;
        }
      }
      // ---- pack + store M1^T (single fp16) ----
      #pragma unroll
      for (int mt = 0; mt < 2; ++mt)
        #pragma unroll
        for (int nt = 0; nt < 2; ++nt) {
          const int idx = (C0 + 16 * nt + lm) * SB + R0 + 16 * mt + 4 * lg;
          *(f16x4*)&M1T[idx] = pack4(acc1[mt][nt]);
        }
    } else if (wv == 4) {
      // ---- aux: y, hmu = h.mu ----
      y = emis[t];
      float hm = hb_l[p][l] * mu_l[p][l];
      hm += __shfl_xor(hm, 1);
      hm += __shfl_xor(hm, 2);
      hm += __shfl_xor(hm, 4);
      hm += __shfl_xor(hm, 8);
      hm += __shfl_xor(hm, 16);
      hm += __shfl_xor(hm, 32);
      hmu = hm;
    } else if (wv == 5) {
      if (t + 1 < n) hn = Ht[(size_t)(t + 1) * D + l];
    }
    barrier_lds();   // B1: M1T, wq, vv, Fmu, sred visible

    // ======================= SEGMENT 2 =======================
    if (wv < 4) {
      const float S = rp + sred_l[0] + sred_l[1];
      const float invS = 1.0f / S;
      // w pieces for the rank-1 term
      f32x4 wr0, wr1; float wc0, wc1;
      {
        const f32x4 a0 = *(const f32x4*)&wq_l[0][R0 + 4 * lg];
        const f32x4 b0 = *(const f32x4*)&wq_l[1][R0 + 4 * lg];
        const f32x4 a1 = *(const f32x4*)&wq_l[0][R0 + 16 + 4 * lg];
        const f32x4 b1 = *(const f32x4*)&wq_l[1][R0 + 16 + 4 * lg];
        #pragma unroll
        for (int j = 0; j < 4; ++j) { wr0[j] = a0[j] + b0[j]; wr1[j] = a1[j] + b1[j]; }
        wc0 = (wq_l[0][C0 + lm]      + wq_l[1][C0 + lm])      * invS;
        wc1 = (wq_l[0][C0 + 16 + lm] + wq_l[1][C0 + 16 + lm]) * invS;
      }
      f32x4 acc2[2][2], acc2lo[2][2];
      #pragma unroll
      for (int j = 0; j < 4; ++j) {
        acc2[0][0][j] = Qc[0][0][j] - wr0[j] * wc0;
        acc2[0][1][j] = Qc[0][1][j] - wr0[j] * wc1;
        acc2[1][0][j] = Qc[1][0][j] - wr1[j] * wc0;
        acc2[1][1][j] = Qc[1][1][j] - wr1[j] * wc1;
      }
      #pragma unroll
      for (int mt = 0; mt < 2; ++mt)
        #pragma unroll
        for (int nt = 0; nt < 2; ++nt)
          acc2lo[mt][nt] = (f32x4){0.f, 0.f, 0.f, 0.f};
      #pragma unroll
      for (int kt = 0; kt < 2; ++kt) {
        f16x8 Bf[2];
        #pragma unroll
        for (int nt = 0; nt < 2; ++nt)
          Bf[nt] = *(const f16x8*)&M1T[(C0 + 16 * nt + lm) * SB + 8 * lg + 32 * kt];
        #pragma unroll
        for (int mt = 0; mt < 2; ++mt)
          #pragma unroll
          for (int nt = 0; nt < 2; ++nt) {
            acc2[mt][nt]   = __builtin_amdgcn_mfma_f32_16x16x32_f16(FAhi[mt][kt], Bf[nt], acc2[mt][nt],   0, 0, 0);
            acc2lo[mt][nt] = __builtin_amdgcn_mfma_f32_16x16x32_f16(FAlo[mt][kt], Bf[nt], acc2lo[mt][nt], 0, 0, 0);
          }
      }
      // ---- fold lo-pass, pack + store P' transposed (== P', symmetric) ----
      #pragma unroll
      for (int mt = 0; mt < 2; ++mt)
        #pragma unroll
        for (int nt = 0; nt < 2; ++nt) {
          #pragma unroll
          for (int j = 0; j < 4; ++j)
            acc2[mt][nt][j] += acc2lo[mt][nt][j] * LO_INV;
          const int idx = (C0 + 16 * nt + lm) * SB + R0 + 16 * mt + 4 * lg;
          *(f16x4*)&PL[idx] = pack4(acc2[mt][nt]);
        }
    } else if (wv == 4) {
      const float S = rp + sred_l[0] + sred_l[1];
      const float kg = (y - hmu) / S;
      out[(size_t)t * D + l] = mu_l[p][l] + kg * vv_l[l];
      mu_l[p ^ 1][l] = Fmu_l[l] + kg * (wq_l[0][l] + wq_l[1][l]);
    } else if (wv == 5) {
      if (t + 1 < n) hb_l[p ^ 1][l] = hn;
    }
    barrier_lds();   // B2: P', mu', h ready for next step
  }
}

extern "C" void kernel_launch(void* const* d_in, const int* in_sizes, int n_in,
                              void* d_out, int out_size, void* d_ws, size_t ws_size,
                              hipStream_t stream) {
  (void)n_in; (void)d_ws; (void)ws_size; (void)out_size;
  const float* emis   = (const float*)d_in[0];
  const float* Ht     = (const float*)d_in[1];
  const float* F      = (const float*)d_in[2];
  const float* Q      = (const float*)d_in[3];
  const float* R      = (const float*)d_in[4];
  const float* mu0    = (const float*)d_in[5];
  const float* Sigma0 = (const float*)d_in[6];
  float* out = (float*)d_out;
  const int n = in_sizes[0];
  hipLaunchKernelGGL(kalman_f16, dim3(1), dim3(512), 0, stream,
                     emis, Ht, F, Q, R, mu0, Sigma0, out, n);
}